// Round 5
// baseline (550.437 us; speedup 1.0000x reference)
//
#include <hip/hip_runtime.h>

// CustomAttention: out = softmax((x_t Wq^T + bq)(x_nt Wk^T + bk)^T) (x_nt Wv^T + bv)
// B=8, SQ=SKV=2048, D=1024. fp32 in/out, fp16 MFMA compute (fp32 accumulate).
//
// Round 7: revert to the round-0 128x128 gemm_bt (479 us, best measured; its
// 2-blocks/CU overlap beats every explicit 256^2 pipeline tried in r3-r6) and
// attach the fusion transforms that r6 proved CORRECT but attached to the
// wrong (1-block/CU, lockstep) GEMM where their serial tail was unhidden:
//   ATRANS 0: A fp16, global_load_lds direct   (QK -- round-0 verified path)
//   ATRANS 1: A fp32, fused cast->fp16         (projections; deletes 2 casts)
//   ATRANS 2: A = S fp16, fused exp(S-m)*inv   (PV; deletes softmax kernel;
//             rowstat pre-pass provides per-row max & 1/sum)
// In a 2-block/CU kernel the reg-load + cvt/exp + ds_write tail lands in
// issue gaps covered by the co-resident block (m114 implicit overlap).
// K-loop, LDS swizzle, barriers, epilogue: byte-identical to round-0.
//
// ws layout:
//  [0,64)    S16 (QK out)   [64,65) mrow  [65,66) srow
//  [128,160) Q16  [160,192) K16  [192,224) Vt16  [224,230) Wq16/Wk16/Wv16

typedef _Float16 half8 __attribute__((ext_vector_type(8)));
typedef _Float16 half4v __attribute__((ext_vector_type(4)));
typedef float floatx4 __attribute__((ext_vector_type(4)));

__device__ __forceinline__ void async_copy16(const _Float16* g, _Float16* l) {
  __builtin_amdgcn_global_load_lds(
      (const __attribute__((address_space(1))) void*)g,
      (__attribute__((address_space(3))) void*)l,
      16, 0, 0);
}

// ---------------- cast fp32 -> fp16 (weights only) ----------------
__global__ __launch_bounds__(256) void cast_f32_f16(const float* __restrict__ src,
                                                    _Float16* __restrict__ dst, long n) {
  long i = ((long)blockIdx.x * 256 + threadIdx.x) * 8;
  if (i >= n) return;
  float4 a = *(const float4*)(src + i);
  float4 b = *(const float4*)(src + i + 4);
  half8 h;
  h[0] = (_Float16)a.x; h[1] = (_Float16)a.y; h[2] = (_Float16)a.z; h[3] = (_Float16)a.w;
  h[4] = (_Float16)b.x; h[5] = (_Float16)b.y; h[6] = (_Float16)b.z; h[7] = (_Float16)b.w;
  *(half8*)(dst + i) = h;
}

// ---------------- fp16 BT GEMM: C[m,n] = sum_k A[m,k]*B[n,k] (+bias[n]) ----
// 128x128 tile, BK=64, 256 threads = 4 waves in 2x2 of 64x64, 16x16x32 MFMA.
// LDS tile: 128 rows x 8 granules (16B), physical granule = logical ^ (row&7).
// OMODE 0: fp16 out row-major [*,N] + bias
// OMODE 1: fp16 out V-transposed: row r -> (b=r>>11, s=r&2047), Vt[b][n][s], + bias
// OMODE 2: fp32 out row-major [*,N] per batch (no bias)
// OMODE 3: fp16 out row-major [*,N] per batch (no bias)  [S scores]
// ATRANS 0: A fp16 via global_load_lds | 1: A fp32, fused cast | 2: A fp16,
//           fused exp(A - rowM)*rowS (softmax numerator/denominator applied).
template <int OMODE, int ATRANS>
__global__ __launch_bounds__(256, 2) void gemm_bt(const void* __restrict__ A,
                                                  const _Float16* __restrict__ B,
                                                  const float* __restrict__ bias,
                                                  const float* __restrict__ rowM,
                                                  const float* __restrict__ rowS,
                                                  void* __restrict__ out,
                                                  int K, int N,
                                                  long sA, long sB, long sO) {
  __shared__ __attribute__((aligned(16))) _Float16 As[128 * 64];  // 16 KB
  __shared__ __attribute__((aligned(16))) _Float16 Bs[128 * 64];  // 16 KB

  const int tid = threadIdx.x;
  const int lane = tid & 63;
  const int wave = tid >> 6;
  const long bz = blockIdx.z;

  const long abase = bz * sA + (long)blockIdx.x * 128 * K;
  const _Float16* Ah = (const _Float16*)A + abase;  // ATRANS 0/2
  const float* Af = (const float*)A + abase;        // ATRANS 1
  const _Float16* Bb = B + bz * sB + (long)blockIdx.y * 128 * K;

  const int wm = (wave & 1) * 64;   // wave m-offset within tile
  const int wn = (wave >> 1) * 64;  // wave n-offset
  const int frow = lane & 15;       // fragment row/col
  const int fq = lane >> 4;         // fragment quad (k-group)
  const int fsw = frow & 7;         // fragment-read swizzle key

  floatx4 acc[4][4];
#pragma unroll
  for (int mt = 0; mt < 4; mt++)
#pragma unroll
    for (int nt = 0; nt < 4; nt++)
      acc[mt][nt] = (floatx4){0.f, 0.f, 0.f, 0.f};

  // Staging: 1024 16B-chunks per matrix; thread handles chunks tid+256j, j=0..3.
  // Physical chunk c -> row c>>3, phys granule c&7; fetch logical granule
  // (c&7)^(row&7); row&7 == (tid>>3)&7 for all j -> swizzle key j-invariant.
  const int sr = tid >> 3;                    // base row 0..31 (j adds 32j)
  const int gl = (tid & 7) ^ (sr & 7);        // logical granule to fetch
  const long gOffBase = (long)sr * K + gl * 8;  // element offset (fp16 or fp32)
  const int ldsOff = tid * 8;                 // halfs; j adds 2048

  // PV softmax stats: thread stages rows sr+32j (j=0..3) every K-step.
  float mA0 = 0.f, sA0 = 0.f, mA1 = 0.f, sA1 = 0.f;
  float mA2 = 0.f, sA2 = 0.f, mA3 = 0.f, sA3 = 0.f;
  if (ATRANS == 2) {
    const long gr = bz * 2048 + (long)blockIdx.x * 128 + sr;
    mA0 = rowM[gr];      sA0 = rowS[gr];
    mA1 = rowM[gr + 32]; sA1 = rowS[gr + 32];
    mA2 = rowM[gr + 64]; sA2 = rowS[gr + 64];
    mA3 = rowM[gr + 96]; sA3 = rowS[gr + 96];
  }

  for (int k0 = 0; k0 < K; k0 += 64) {
    __syncthreads();  // previous iter's LDS reads complete before overwrite
    if (ATRANS == 0) {
#pragma unroll
      for (int j = 0; j < 4; j++) {
        async_copy16(Ah + gOffBase + (long)(32 * j) * K + k0, As + ldsOff + j * 2048);
        async_copy16(Bb + gOffBase + (long)(32 * j) * K + k0, Bs + ldsOff + j * 2048);
      }
    } else if (ATRANS == 1) {
      floatx4 f0[4], f1[4];
#pragma unroll
      for (int j = 0; j < 4; j++) {  // issue A fp32 loads first (latency hidden
        const float* src = Af + gOffBase + (long)(32 * j) * K + k0;  // by co-block)
        f0[j] = *(const floatx4*)(src);
        f1[j] = *(const floatx4*)(src + 4);
      }
#pragma unroll
      for (int j = 0; j < 4; j++)
        async_copy16(Bb + gOffBase + (long)(32 * j) * K + k0, Bs + ldsOff + j * 2048);
#pragma unroll
      for (int j = 0; j < 4; j++) {
        half8 w;
#pragma unroll
        for (int t = 0; t < 4; t++) {
          w[t] = (_Float16)f0[j][t];
          w[4 + t] = (_Float16)f1[j][t];
        }
        *(half8*)(As + ldsOff + j * 2048) = w;
      }
    } else {  // ATRANS == 2
      half8 hv[4];
#pragma unroll
      for (int j = 0; j < 4; j++)
        hv[j] = *(const half8*)(Ah + gOffBase + (long)(32 * j) * K + k0);
#pragma unroll
      for (int j = 0; j < 4; j++)
        async_copy16(Bb + gOffBase + (long)(32 * j) * K + k0, Bs + ldsOff + j * 2048);
#pragma unroll
      for (int j = 0; j < 4; j++) {
        const float mj = (j == 0) ? mA0 : (j == 1) ? mA1 : (j == 2) ? mA2 : mA3;
        const float sj = (j == 0) ? sA0 : (j == 1) ? sA1 : (j == 2) ? sA2 : sA3;
        half8 w;
#pragma unroll
        for (int t = 0; t < 8; t++)
          w[t] = (_Float16)(__expf((float)hv[j][t] - mj) * sj);
        *(half8*)(As + ldsOff + j * 2048) = w;
      }
    }
    __syncthreads();  // vmcnt+lgkm drain before barrier -> LDS visible

#pragma unroll
    for (int h = 0; h < 2; h++) {
      half8 af[4], bf[4];
#pragma unroll
      for (int mt = 0; mt < 4; mt++)
        af[mt] = *(const half8*)(As + (wm + mt * 16 + frow) * 64 + ((h * 4 + fq) ^ fsw) * 8);
#pragma unroll
      for (int nt = 0; nt < 4; nt++)
        bf[nt] = *(const half8*)(Bs + (wn + nt * 16 + frow) * 64 + ((h * 4 + fq) ^ fsw) * 8);
#pragma unroll
      for (int mt = 0; mt < 4; mt++)
#pragma unroll
        for (int nt = 0; nt < 4; nt++)
          acc[mt][nt] = __builtin_amdgcn_mfma_f32_16x16x32_f16(af[mt], bf[nt], acc[mt][nt], 0, 0, 0);
    }
  }

  // C/D layout: acc[mt][nt][i] = C[wm+mt*16+fq*4+i][wn+nt*16+frow]
  if (OMODE == 2 || OMODE == 3) {
#pragma unroll
    for (int nt = 0; nt < 4; nt++) {
      const int n = blockIdx.y * 128 + wn + nt * 16 + frow;
#pragma unroll
      for (int mt = 0; mt < 4; mt++) {
        const int rbase = blockIdx.x * 128 + wm + mt * 16 + fq * 4;
#pragma unroll
        for (int i = 0; i < 4; i++) {
          if (OMODE == 2)
            ((float*)out + bz * sO)[(long)(rbase + i) * N + n] = acc[mt][nt][i];
          else
            ((_Float16*)out + bz * sO)[(long)(rbase + i) * N + n] = (_Float16)acc[mt][nt][i];
        }
      }
    }
  } else {
#pragma unroll
    for (int nt = 0; nt < 4; nt++) {
      const int n = blockIdx.y * 128 + wn + nt * 16 + frow;
      const float bvv = bias[n];
#pragma unroll
      for (int mt = 0; mt < 4; mt++) {
        const int rbase = blockIdx.x * 128 + wm + mt * 16 + fq * 4;
        if (OMODE == 0) {
#pragma unroll
          for (int i = 0; i < 4; i++)
            ((_Float16*)out)[(long)(rbase + i) * N + n] = (_Float16)(acc[mt][nt][i] + bvv);
        } else {  // OMODE 1: Vt[b][n][s], s = rbase..rbase+3 contiguous -> 8B store
          const long bb = rbase >> 11;
          const int s = rbase & 2047;
          half4v hv;
#pragma unroll
          for (int i = 0; i < 4; i++) hv[i] = (_Float16)(acc[mt][nt][i] + bvv);
          *(half4v*)((_Float16*)out + bb * (2048l * 1024) + (long)n * 2048 + s) = hv;
        }
      }
    }
  }
}

// ---------------- row stats: S fp16 [rows][2048] -> max, 1/sum -------------
__global__ __launch_bounds__(256) void rowstat(const _Float16* __restrict__ S,
                                               float* __restrict__ rowM,
                                               float* __restrict__ rowS) {
  const long row = blockIdx.x;
  const _Float16* src = S + row * 2048;
  const int tid = threadIdx.x;

  half8 v = ((const half8*)src)[tid];
  float f[8];
#pragma unroll
  for (int i = 0; i < 8; i++) f[i] = (float)v[i];

  float m = fmaxf(fmaxf(fmaxf(f[0], f[1]), fmaxf(f[2], f[3])),
                  fmaxf(fmaxf(f[4], f[5]), fmaxf(f[6], f[7])));
#pragma unroll
  for (int o = 32; o > 0; o >>= 1) m = fmaxf(m, __shfl_xor(m, o, 64));
  __shared__ float redm[4];
  if ((tid & 63) == 0) redm[tid >> 6] = m;
  __syncthreads();
  m = fmaxf(fmaxf(redm[0], redm[1]), fmaxf(redm[2], redm[3]));

  float s = 0.f;
#pragma unroll
  for (int i = 0; i < 8; i++) s += __expf(f[i] - m);
#pragma unroll
  for (int o = 32; o > 0; o >>= 1) s += __shfl_xor(s, o, 64);
  __shared__ float reds[4];
  if ((tid & 63) == 0) reds[tid >> 6] = s;
  __syncthreads();
  s = (reds[0] + reds[1]) + (reds[2] + reds[3]);

  if (tid == 0) {
    rowM[row] = m;
    rowS[row] = 1.f / s;
  }
}

extern "C" void kernel_launch(void* const* d_in, const int* in_sizes, int n_in,
                              void* d_out, int out_size, void* d_ws, size_t ws_size,
                              hipStream_t stream) {
  const float* target = (const float*)d_in[0];
  const float* non_target = (const float*)d_in[1];
  const float* Wq = (const float*)d_in[2];
  const float* bq = (const float*)d_in[3];
  const float* Wk = (const float*)d_in[4];
  const float* bk = (const float*)d_in[5];
  const float* Wv = (const float*)d_in[6];
  const float* bv = (const float*)d_in[7];

  char* ws = (char*)d_ws;
  const size_t MB = 1ull << 20;
  _Float16* S16 = (_Float16*)(ws);               // 64 MiB
  float* mrow = (float*)(ws + 64 * MB);          // 64 KiB
  float* srow = (float*)(ws + 65 * MB);          // 64 KiB
  _Float16* Q16 = (_Float16*)(ws + 128 * MB);    // 32 MiB
  _Float16* K16 = (_Float16*)(ws + 160 * MB);    // 32 MiB
  _Float16* Vt16 = (_Float16*)(ws + 192 * MB);   // 32 MiB
  _Float16* Wq16 = (_Float16*)(ws + 224 * MB);   // 2 MiB
  _Float16* Wk16 = (_Float16*)(ws + 226 * MB);   // 2 MiB
  _Float16* Wv16 = (_Float16*)(ws + 228 * MB);   // 2 MiB

  const long nW = 1024l * 1024;

  // 1. weight casts only (activation casts fused into projection staging)
  cast_f32_f16<<<512, 256, 0, stream>>>(Wq, Wq16, nW);
  cast_f32_f16<<<512, 256, 0, stream>>>(Wk, Wk16, nW);
  cast_f32_f16<<<512, 256, 0, stream>>>(Wv, Wv16, nW);

  // 2. projections (A = fp32 source, fused cast): [16384,1024] x [1024,1024]^T + bias
  gemm_bt<0, 1><<<dim3(128, 8, 1), 256, 0, stream>>>(target, Wq16, bq, nullptr, nullptr,
                                                     Q16, 1024, 1024, 0, 0, 0);
  gemm_bt<0, 1><<<dim3(128, 8, 1), 256, 0, stream>>>(non_target, Wk16, bk, nullptr, nullptr,
                                                     K16, 1024, 1024, 0, 0, 0);
  gemm_bt<1, 1><<<dim3(128, 8, 1), 256, 0, stream>>>(non_target, Wv16, bv, nullptr, nullptr,
                                                     Vt16, 1024, 1024, 0, 0, 0);

  // 3. scores: per batch [2048,2048] = Q_b x K_b^T (fp16 out)
  gemm_bt<3, 0><<<dim3(16, 16, 8), 256, 0, stream>>>(Q16, K16, nullptr, nullptr, nullptr,
                                                     S16, 1024, 2048,
                                                     2048l * 1024, 2048l * 1024, 2048l * 2048);

  // 4. row stats (max, 1/sum) for the fused softmax in PV
  rowstat<<<16384, 256, 0, stream>>>(S16, mrow, srow);

  // 5. out: per batch [2048,1024] = softmax(S)_b x Vt_b^T (fp32 out), fused
  //    exp(S-m)*inv in A-staging
  gemm_bt<2, 2><<<dim3(16, 8, 8), 256, 0, stream>>>(S16, Vt16, nullptr, mrow, srow,
                                                    (float*)d_out, 2048, 1024,
                                                    2048l * 2048, 1024l * 2048, 2048l * 1024);
}

// Round 6
// 465.718 us; speedup vs baseline: 1.1819x; 1.1819x over previous
//
#include <hip/hip_runtime.h>

// CustomAttention: out = softmax((x_t Wq^T + bq)(x_nt Wk^T + bk)^T) (x_nt Wv^T + bv)
// B=8, SQ=SKV=2048, D=1024. fp32 in/out, fp16 MFMA compute (fp32 accumulate).
//
// Round 8: round-0 (479 us, best measured) with IDENTICAL per-element compute,
// repackaged to attack the ~135 us of launch/packaging overhead:
//  - 5 dispatches instead of 11: merged cast (5 regions in one grid), merged
//    Q/K/V projection (grid.z=3, uniform selects; weights/outputs contiguous
//    in ws), QK, softmax, PV.
//  - XCD-aware bijective block swizzle on QK (per-XCD 4x8 panel region, 3 MB
//    < 4 MB L2) and PV (4x4, 4 MB) -- r0 QK FETCH=148 MB vs 64 ideal.
// K-loop, LDS XOR-swizzle, epilogues, softmax: byte-identical math to r0.
// Fusion (cast/softmax into GEMM staging) measured DEAD: r6=508, r7=550 --
// exp re-executed grid.y times (8x) swamps the saved kernels.
//
// ws layout (r0): [0,32) tgt16 | [32,64) ntg16  (dead after proj; S16 [0,64))
//  [64,128) P16  [128,160) Q16  [160,192) K16  [192,224) Vt16
//  [224,226) Wq16 [226,228) Wk16 [228,230) Wv16

typedef _Float16 half8 __attribute__((ext_vector_type(8)));
typedef _Float16 half4v __attribute__((ext_vector_type(4)));
typedef float floatx4 __attribute__((ext_vector_type(4)));

__device__ __forceinline__ void async_copy16(const _Float16* g, _Float16* l) {
  __builtin_amdgcn_global_load_lds(
      (const __attribute__((address_space(1))) void*)g,
      (__attribute__((address_space(3))) void*)l,
      16, 0, 0);
}

// ---------------- merged cast fp32 -> fp16 (all 5 tensors, one launch) -----
// blocks [0,8192): target->tgt16 | [8192,16384): non_target->ntg16
// [16384,16896): Wq | [16896,17408): Wk | [17408,17920): Wv
__global__ __launch_bounds__(256) void cast_all(const float* __restrict__ t,
                                                const float* __restrict__ nt,
                                                const float* __restrict__ wq,
                                                const float* __restrict__ wk,
                                                const float* __restrict__ wv,
                                                _Float16* __restrict__ tgt16,
                                                _Float16* __restrict__ ntg16,
                                                _Float16* __restrict__ wq16,
                                                _Float16* __restrict__ wk16,
                                                _Float16* __restrict__ wv16) {
  const int b = blockIdx.x;
  const float* src;
  _Float16* dst;
  long base;
  if (b < 8192)       { src = t;  dst = tgt16; base = (long)b * 2048; }
  else if (b < 16384) { src = nt; dst = ntg16; base = (long)(b - 8192) * 2048; }
  else if (b < 16896) { src = wq; dst = wq16;  base = (long)(b - 16384) * 2048; }
  else if (b < 17408) { src = wk; dst = wk16;  base = (long)(b - 16896) * 2048; }
  else                { src = wv; dst = wv16;  base = (long)(b - 17408) * 2048; }
  const long i = base + (long)threadIdx.x * 8;
  float4 a = *(const float4*)(src + i);
  float4 c = *(const float4*)(src + i + 4);
  half8 h;
  h[0] = (_Float16)a.x; h[1] = (_Float16)a.y; h[2] = (_Float16)a.z; h[3] = (_Float16)a.w;
  h[4] = (_Float16)c.x; h[5] = (_Float16)c.y; h[6] = (_Float16)c.z; h[7] = (_Float16)c.w;
  *(half8*)(dst + i) = h;
}

// ---------------- fp16 BT GEMM: C[m,n] = sum_k A[m,k]*B[n,k] (+bias[n]) ----
// 128x128 tile, BK=64, 256 threads = 4 waves in 2x2 of 64x64, 16x16x32 MFMA.
// LDS tile: 128 rows x 8 granules (16B), physical granule = logical ^ (row&7)
// (XOR swizzle, measured conflict-free). Byte-identical K-loop to round-0.
// OMODE 2: fp32 out row-major per batch (PV)
// OMODE 3: fp16 out row-major per batch (QK scores)
// OMODE 4: merged projections, grid.z selects {Q,K,V}: A = base + (bz?sA:0),
//          B = base + bz*sB, bias = {bias,biasK,biasV}[bz], out = base + bz*sO;
//          bz<2: fp16 row-major + bias; bz==2: fp16 V-transposed + bias.
// SWZ 1: QK 16x16/batch -> per-XCD 4x8 region. SWZ 2: PV 16x8 -> 4x4 region.
template <int OMODE, int SWZ>
__global__ __launch_bounds__(256, 2) void gemm_bt(const _Float16* __restrict__ A,
                                                  const _Float16* __restrict__ B,
                                                  const float* __restrict__ bias,
                                                  const float* __restrict__ biasK,
                                                  const float* __restrict__ biasV,
                                                  void* __restrict__ out,
                                                  int K, int N,
                                                  long sA, long sB, long sO) {
  __shared__ __attribute__((aligned(16))) _Float16 As[128 * 64];  // 16 KB
  __shared__ __attribute__((aligned(16))) _Float16 Bs[128 * 64];  // 16 KB

  const int tid = threadIdx.x;
  const int lane = tid & 63;
  const int wave = tid >> 6;
  const long bz = blockIdx.z;

  // XCD-aware bijective swizzle (per-batch 2D grid; grid.x*grid.y % 8 == 0 so
  // h%8 tracks the linear-dispatch XCD round-robin).
  int bx = blockIdx.x, by = blockIdx.y;
  if (SWZ == 1) {  // grid (16,16): XCD g owns bx in [4(g&3),+4), by in [8(g>>2),+8)
    const int h = bx + 16 * by, g = h & 7, idx = h >> 3;  // idx 0..31
    bx = (g & 3) * 4 + (idx & 3);
    by = (g >> 2) * 8 + (idx >> 2);
  } else if (SWZ == 2) {  // grid (16,8): XCD g owns 4x4 region
    const int h = bx + 16 * by, g = h & 7, idx = h >> 3;  // idx 0..15
    bx = (g & 3) * 4 + (idx & 3);
    by = (g >> 2) * 4 + (idx >> 2);
  }

  const long abase = (OMODE == 4 ? (bz ? sA : 0) : bz * sA) + (long)bx * 128 * K;
  const _Float16* Ab = A + abase;
  const _Float16* Bb = B + bz * sB + (long)by * 128 * K;

  const int wm = (wave & 1) * 64;   // wave m-offset within tile
  const int wn = (wave >> 1) * 64;  // wave n-offset
  const int frow = lane & 15;       // fragment row/col
  const int fq = lane >> 4;         // fragment quad (k-group)
  const int fsw = frow & 7;         // fragment-read swizzle key

  floatx4 acc[4][4];
#pragma unroll
  for (int mt = 0; mt < 4; mt++)
#pragma unroll
    for (int nt = 0; nt < 4; nt++)
      acc[mt][nt] = (floatx4){0.f, 0.f, 0.f, 0.f};

  // Staging: 1024 16B-chunks per matrix; thread handles chunks tid+256j, j=0..3.
  // Physical chunk c -> row c>>3, phys granule c&7; fetch logical granule
  // (c&7)^(row&7); row&7 == (tid>>3)&7 for all j -> swizzle key j-invariant.
  const int sr = tid >> 3;                    // base row 0..31 (j adds 32j)
  const int gl = (tid & 7) ^ (sr & 7);        // logical granule to fetch
  const long gOffBase = (long)sr * K + gl * 8;
  const int ldsOff = tid * 8;                 // halfs; j adds 2048

  for (int k0 = 0; k0 < K; k0 += 64) {
    __syncthreads();  // previous iter's LDS reads complete before overwrite
#pragma unroll
    for (int j = 0; j < 4; j++) {
      async_copy16(Ab + gOffBase + (long)(32 * j) * K + k0, As + ldsOff + j * 2048);
      async_copy16(Bb + gOffBase + (long)(32 * j) * K + k0, Bs + ldsOff + j * 2048);
    }
    __syncthreads();  // vmcnt(0) drain before barrier -> LDS visible

#pragma unroll
    for (int h = 0; h < 2; h++) {
      half8 af[4], bf[4];
#pragma unroll
      for (int mt = 0; mt < 4; mt++)
        af[mt] = *(const half8*)(As + (wm + mt * 16 + frow) * 64 + ((h * 4 + fq) ^ fsw) * 8);
#pragma unroll
      for (int nt = 0; nt < 4; nt++)
        bf[nt] = *(const half8*)(Bs + (wn + nt * 16 + frow) * 64 + ((h * 4 + fq) ^ fsw) * 8);
#pragma unroll
      for (int mt = 0; mt < 4; mt++)
#pragma unroll
        for (int nt = 0; nt < 4; nt++)
          acc[mt][nt] = __builtin_amdgcn_mfma_f32_16x16x32_f16(af[mt], bf[nt], acc[mt][nt], 0, 0, 0);
    }
  }

  // C/D layout: acc[mt][nt][i] = C[wm+mt*16+fq*4+i][wn+nt*16+frow]
  if (OMODE == 2 || OMODE == 3) {
#pragma unroll
    for (int nt = 0; nt < 4; nt++) {
      const int n = by * 128 + wn + nt * 16 + frow;
#pragma unroll
      for (int mt = 0; mt < 4; mt++) {
        const int rbase = bx * 128 + wm + mt * 16 + fq * 4;
#pragma unroll
        for (int i = 0; i < 4; i++) {
          if (OMODE == 2)
            ((float*)out + bz * sO)[(long)(rbase + i) * N + n] = acc[mt][nt][i];
          else
            ((_Float16*)out + bz * sO)[(long)(rbase + i) * N + n] = (_Float16)acc[mt][nt][i];
        }
      }
    }
  } else {  // OMODE == 4: merged projections
    const float* bp = (bz == 0) ? bias : (bz == 1) ? biasK : biasV;
#pragma unroll
    for (int nt = 0; nt < 4; nt++) {
      const int n = by * 128 + wn + nt * 16 + frow;
      const float bvv = bp[n];
#pragma unroll
      for (int mt = 0; mt < 4; mt++) {
        const int rbase = bx * 128 + wm + mt * 16 + fq * 4;
        if (bz < 2) {  // Q16 / K16 row-major fp16
          _Float16* o16 = (_Float16*)out + bz * sO;
#pragma unroll
          for (int i = 0; i < 4; i++)
            o16[(long)(rbase + i) * N + n] = (_Float16)(acc[mt][nt][i] + bvv);
        } else {  // Vt16[b][n][s], s = rbase..rbase+3 contiguous -> 8B store
          _Float16* vt = (_Float16*)out + 2 * sO;
          const long bb = rbase >> 11;
          const int s = rbase & 2047;
          half4v hv;
#pragma unroll
          for (int i = 0; i < 4; i++) hv[i] = (_Float16)(acc[mt][nt][i] + bvv);
          *(half4v*)(vt + bb * (2048l * 1024) + (long)n * 2048 + s) = hv;
        }
      }
    }
  }
}

// ---------------- row softmax: S fp16 [rows][2048] -> P fp16 ----------------
__global__ __launch_bounds__(256) void softmax_rows(const _Float16* __restrict__ S,
                                                    _Float16* __restrict__ P) {
  const long row = blockIdx.x;
  const _Float16* src = S + row * 2048;
  _Float16* dst = P + row * 2048;
  const int tid = threadIdx.x;

  half8 v = ((const half8*)src)[tid];  // elems 8t..8t+7
  float f[8];
#pragma unroll
  for (int i = 0; i < 8; i++) f[i] = (float)v[i];

  float m = fmaxf(fmaxf(fmaxf(f[0], f[1]), fmaxf(f[2], f[3])),
                  fmaxf(fmaxf(f[4], f[5]), fmaxf(f[6], f[7])));
#pragma unroll
  for (int o = 32; o > 0; o >>= 1) m = fmaxf(m, __shfl_xor(m, o, 64));
  __shared__ float redm[4];
  if ((tid & 63) == 0) redm[tid >> 6] = m;
  __syncthreads();
  m = fmaxf(fmaxf(redm[0], redm[1]), fmaxf(redm[2], redm[3]));

  float e[8], s = 0.f;
#pragma unroll
  for (int i = 0; i < 8; i++) { e[i] = __expf(f[i] - m); s += e[i]; }
#pragma unroll
  for (int o = 32; o > 0; o >>= 1) s += __shfl_xor(s, o, 64);
  __shared__ float reds[4];
  if ((tid & 63) == 0) reds[tid >> 6] = s;
  __syncthreads();
  s = (reds[0] + reds[1]) + (reds[2] + reds[3]);
  const float inv = 1.f / s;

  half8 h;
#pragma unroll
  for (int i = 0; i < 8; i++) h[i] = (_Float16)(e[i] * inv);
  ((half8*)dst)[tid] = h;
}

extern "C" void kernel_launch(void* const* d_in, const int* in_sizes, int n_in,
                              void* d_out, int out_size, void* d_ws, size_t ws_size,
                              hipStream_t stream) {
  const float* target = (const float*)d_in[0];
  const float* non_target = (const float*)d_in[1];
  const float* Wq = (const float*)d_in[2];
  const float* bq = (const float*)d_in[3];
  const float* Wk = (const float*)d_in[4];
  const float* bk = (const float*)d_in[5];
  const float* Wv = (const float*)d_in[6];
  const float* bv = (const float*)d_in[7];

  char* ws = (char*)d_ws;
  const size_t MB = 1ull << 20;
  _Float16* tgt16 = (_Float16*)(ws);             // 32 MiB
  _Float16* ntg16 = (_Float16*)(ws + 32 * MB);   // 32 MiB
  _Float16* S16 = (_Float16*)(ws);               // 64 MiB (over tgt16/ntg16)
  _Float16* P16 = (_Float16*)(ws + 64 * MB);     // 64 MiB
  _Float16* Q16 = (_Float16*)(ws + 128 * MB);    // 32 MiB
  _Float16* K16 = (_Float16*)(ws + 160 * MB);    // 32 MiB
  _Float16* Wq16 = (_Float16*)(ws + 224 * MB);   // 2 MiB (Wk16/Wv16 contiguous)
  _Float16* Wk16 = (_Float16*)(ws + 226 * MB);
  _Float16* Wv16 = (_Float16*)(ws + 228 * MB);
  _Float16* Vt16 = (_Float16*)(ws + 192 * MB);   // 32 MiB

  // 1. all casts, one launch (17920 blocks: 2x8192 activations + 3x512 weights)
  cast_all<<<17920, 256, 0, stream>>>(target, non_target, Wq, Wk, Wv,
                                      tgt16, ntg16, Wq16, Wk16, Wv16);

  // 2. merged projections, one launch: grid.z in {Q,K,V}.
  //    A: tgt16 (bz=0) / ntg16 (bz>0) via sA=16Mi halfs; B: Wq16+bz*1Mi;
  //    out: Q16+bz*16Mi (Q16,K16,Vt16 contiguous at 128/160/192 MiB).
  gemm_bt<4, 0><<<dim3(128, 8, 3), 256, 0, stream>>>(
      tgt16, Wq16, bq, bk, bv, Q16, 1024, 1024,
      16777216l, 1048576l, 16777216l);

  // 3. scores: per batch [2048,2048] = Q_b x K_b^T (fp16 out), XCD swizzle
  gemm_bt<3, 1><<<dim3(16, 16, 8), 256, 0, stream>>>(
      Q16, K16, nullptr, nullptr, nullptr, S16, 1024, 2048,
      2048l * 1024, 2048l * 1024, 2048l * 2048);

  // 4. softmax rows -> P fp16
  softmax_rows<<<16384, 256, 0, stream>>>(S16, P16);

  // 5. out: per batch [2048,1024] = P_b x Vt_b^T (fp32 out), XCD swizzle
  gemm_bt<2, 2><<<dim3(16, 8, 8), 256, 0, stream>>>(
      P16, Vt16, nullptr, nullptr, nullptr, (float*)d_out, 2048, 1024,
      2048l * 2048, 1024l * 2048, 2048l * 1024);
}

// Round 7
// 453.338 us; speedup vs baseline: 1.2142x; 1.0273x over previous
//
#include <hip/hip_runtime.h>

// CustomAttention: out = softmax((x_t Wq^T + bq)(x_nt Wk^T + bk)^T) (x_nt Wv^T + bv)
// B=8, SQ=SKV=2048, D=1024. fp32 in/out, fp16 MFMA compute (fp32 accumulate).
//
// Round 9: round-8 (465.7 us, best measured) + ONE change: the Vt epilogue of
// the merged projection (z==2) now transposes the C-tile through LDS and emits
// coalesced 16B stores (16 lanes -> 256B contiguous), replacing 8B stores at
// 4KB stride that showed as +58 MB WRITE_SIZE amplification (154 vs 96 ideal)
// on the #1 dispatch (140 us). Identical math/rounding everywhere.
// Kept from r8: 5-dispatch packaging (merged cast, merged Q/K/V projection,
// QK, softmax, PV), XCD swizzle on QK/PV, verified 128x128 BK=64 K-loop with
// XOR-swizzled global_load_lds staging (bank-conflict counter 0).
// Measured dead, do not revisit: cast/softmax fusion into GEMM staging
// (r6=508, r7=550 -- exp re-executed grid.y times); 256^2 pipelined schedules
// (r3=84.2, r4=81.0 vs r0 81.7 us QK -- all at the ~846 TF structure ceiling).
//
// ws layout: [0,32) tgt16 | [32,64) ntg16 (dead after proj; S16 [0,64))
//  [64,128) P16  [128,160) Q16  [160,192) K16  [192,224) Vt16
//  [224,226) Wq16 [226,228) Wk16 [228,230) Wv16

typedef _Float16 half8 __attribute__((ext_vector_type(8)));
typedef _Float16 half4v __attribute__((ext_vector_type(4)));
typedef float floatx4 __attribute__((ext_vector_type(4)));

__device__ __forceinline__ void async_copy16(const _Float16* g, _Float16* l) {
  __builtin_amdgcn_global_load_lds(
      (const __attribute__((address_space(1))) void*)g,
      (__attribute__((address_space(3))) void*)l,
      16, 0, 0);
}

// ---------------- merged cast fp32 -> fp16 (all 5 tensors, one launch) -----
// blocks [0,8192): target->tgt16 | [8192,16384): non_target->ntg16
// [16384,16896): Wq | [16896,17408): Wk | [17408,17920): Wv
__global__ __launch_bounds__(256) void cast_all(const float* __restrict__ t,
                                                const float* __restrict__ nt,
                                                const float* __restrict__ wq,
                                                const float* __restrict__ wk,
                                                const float* __restrict__ wv,
                                                _Float16* __restrict__ tgt16,
                                                _Float16* __restrict__ ntg16,
                                                _Float16* __restrict__ wq16,
                                                _Float16* __restrict__ wk16,
                                                _Float16* __restrict__ wv16) {
  const int b = blockIdx.x;
  const float* src;
  _Float16* dst;
  long base;
  if (b < 8192)       { src = t;  dst = tgt16; base = (long)b * 2048; }
  else if (b < 16384) { src = nt; dst = ntg16; base = (long)(b - 8192) * 2048; }
  else if (b < 16896) { src = wq; dst = wq16;  base = (long)(b - 16384) * 2048; }
  else if (b < 17408) { src = wk; dst = wk16;  base = (long)(b - 16896) * 2048; }
  else                { src = wv; dst = wv16;  base = (long)(b - 17408) * 2048; }
  const long i = base + (long)threadIdx.x * 8;
  float4 a = *(const float4*)(src + i);
  float4 c = *(const float4*)(src + i + 4);
  half8 h;
  h[0] = (_Float16)a.x; h[1] = (_Float16)a.y; h[2] = (_Float16)a.z; h[3] = (_Float16)a.w;
  h[4] = (_Float16)c.x; h[5] = (_Float16)c.y; h[6] = (_Float16)c.z; h[7] = (_Float16)c.w;
  *(half8*)(dst + i) = h;
}

// ---------------- fp16 BT GEMM: C[m,n] = sum_k A[m,k]*B[n,k] (+bias[n]) ----
// 128x128 tile, BK=64, 256 threads = 4 waves in 2x2 of 64x64, 16x16x32 MFMA.
// LDS tile: 128 rows x 8 granules (16B), physical granule = logical ^ (row&7)
// (XOR swizzle, measured conflict-free). Byte-identical K-loop to round-0.
// OMODE 2: fp32 out row-major per batch (PV)
// OMODE 3: fp16 out row-major per batch (QK scores)
// OMODE 4: merged projections, grid.z selects {Q,K,V}: A = base + (bz?sA:0),
//          B = base + bz*sB, bias = {bias,biasK,biasV}[bz], out = base + bz*sO;
//          bz<2: fp16 row-major + bias; bz==2: fp16 V-transposed + bias via
//          LDS-transpose epilogue (coalesced 16B stores).
// SWZ 1: QK 16x16/batch -> per-XCD 4x8 region. SWZ 2: PV 16x8 -> 4x4 region.
template <int OMODE, int SWZ>
__global__ __launch_bounds__(256, 2) void gemm_bt(const _Float16* __restrict__ A,
                                                  const _Float16* __restrict__ B,
                                                  const float* __restrict__ bias,
                                                  const float* __restrict__ biasK,
                                                  const float* __restrict__ biasV,
                                                  void* __restrict__ out,
                                                  int K, int N,
                                                  long sA, long sB, long sO) {
  // single 32 KB buffer: As = [0,8192) halfs, Bs = [8192,16384); the Vt
  // epilogue reuses the whole buffer as a 128x128 fp16 transpose tile.
  __shared__ __attribute__((aligned(16))) _Float16 smem[2 * 128 * 64];
  _Float16* As = smem;
  _Float16* Bs = smem + 8192;

  const int tid = threadIdx.x;
  const int lane = tid & 63;
  const int wave = tid >> 6;
  const long bz = blockIdx.z;

  // XCD-aware bijective swizzle (per-batch 2D grid; grid.x*grid.y % 8 == 0 so
  // h%8 tracks the linear-dispatch XCD round-robin).
  int bx = blockIdx.x, by = blockIdx.y;
  if (SWZ == 1) {  // grid (16,16): XCD g owns bx in [4(g&3),+4), by in [8(g>>2),+8)
    const int h = bx + 16 * by, g = h & 7, idx = h >> 3;  // idx 0..31
    bx = (g & 3) * 4 + (idx & 3);
    by = (g >> 2) * 8 + (idx >> 2);
  } else if (SWZ == 2) {  // grid (16,8): XCD g owns 4x4 region
    const int h = bx + 16 * by, g = h & 7, idx = h >> 3;  // idx 0..15
    bx = (g & 3) * 4 + (idx & 3);
    by = (g >> 2) * 4 + (idx >> 2);
  }

  const long abase = (OMODE == 4 ? (bz ? sA : 0) : bz * sA) + (long)bx * 128 * K;
  const _Float16* Ab = A + abase;
  const _Float16* Bb = B + bz * sB + (long)by * 128 * K;

  const int wm = (wave & 1) * 64;   // wave m-offset within tile
  const int wn = (wave >> 1) * 64;  // wave n-offset
  const int frow = lane & 15;       // fragment row/col
  const int fq = lane >> 4;         // fragment quad (k-group)
  const int fsw = frow & 7;         // fragment-read swizzle key

  floatx4 acc[4][4];
#pragma unroll
  for (int mt = 0; mt < 4; mt++)
#pragma unroll
    for (int nt = 0; nt < 4; nt++)
      acc[mt][nt] = (floatx4){0.f, 0.f, 0.f, 0.f};

  // Staging: 1024 16B-chunks per matrix; thread handles chunks tid+256j, j=0..3.
  // Physical chunk c -> row c>>3, phys granule c&7; fetch logical granule
  // (c&7)^(row&7); row&7 == (tid>>3)&7 for all j -> swizzle key j-invariant.
  const int sr = tid >> 3;                    // base row 0..31 (j adds 32j)
  const int gl = (tid & 7) ^ (sr & 7);        // logical granule to fetch
  const long gOffBase = (long)sr * K + gl * 8;
  const int ldsOff = tid * 8;                 // halfs; j adds 2048

  for (int k0 = 0; k0 < K; k0 += 64) {
    __syncthreads();  // previous iter's LDS reads complete before overwrite
#pragma unroll
    for (int j = 0; j < 4; j++) {
      async_copy16(Ab + gOffBase + (long)(32 * j) * K + k0, As + ldsOff + j * 2048);
      async_copy16(Bb + gOffBase + (long)(32 * j) * K + k0, Bs + ldsOff + j * 2048);
    }
    __syncthreads();  // vmcnt(0) drain before barrier -> LDS visible

#pragma unroll
    for (int h = 0; h < 2; h++) {
      half8 af[4], bf[4];
#pragma unroll
      for (int mt = 0; mt < 4; mt++)
        af[mt] = *(const half8*)(As + (wm + mt * 16 + frow) * 64 + ((h * 4 + fq) ^ fsw) * 8);
#pragma unroll
      for (int nt = 0; nt < 4; nt++)
        bf[nt] = *(const half8*)(Bs + (wn + nt * 16 + frow) * 64 + ((h * 4 + fq) ^ fsw) * 8);
#pragma unroll
      for (int mt = 0; mt < 4; mt++)
#pragma unroll
        for (int nt = 0; nt < 4; nt++)
          acc[mt][nt] = __builtin_amdgcn_mfma_f32_16x16x32_f16(af[mt], bf[nt], acc[mt][nt], 0, 0, 0);
    }
  }

  // C/D layout: acc[mt][nt][i] = C[wm+mt*16+fq*4+i][wn+nt*16+frow]
  if (OMODE == 2 || OMODE == 3) {
#pragma unroll
    for (int nt = 0; nt < 4; nt++) {
      const int n = by * 128 + wn + nt * 16 + frow;
#pragma unroll
      for (int mt = 0; mt < 4; mt++) {
        const int rbase = bx * 128 + wm + mt * 16 + fq * 4;
#pragma unroll
        for (int i = 0; i < 4; i++) {
          if (OMODE == 2)
            ((float*)out + bz * sO)[(long)(rbase + i) * N + n] = acc[mt][nt][i];
          else
            ((_Float16*)out + bz * sO)[(long)(rbase + i) * N + n] = (_Float16)acc[mt][nt][i];
        }
      }
    }
  } else {  // OMODE == 4: merged projections
    const float* bp = (bz == 0) ? bias : (bz == 1) ? biasK : biasV;
    if (bz < 2) {  // Q16 / K16 row-major fp16
#pragma unroll
      for (int nt = 0; nt < 4; nt++) {
        const int n = by * 128 + wn + nt * 16 + frow;
        const float bvv = bp[n];
        _Float16* o16 = (_Float16*)out + bz * sO;
#pragma unroll
        for (int mt = 0; mt < 4; mt++) {
          const int rbase = bx * 128 + wm + mt * 16 + fq * 4;
#pragma unroll
          for (int i = 0; i < 4; i++)
            o16[(long)(rbase + i) * N + n] = (_Float16)(acc[mt][nt][i] + bvv);
        }
      }
    } else {
      // Vt[b][n][s] via LDS transpose: T[c][r] halfs with 8-half granule XOR,
      // addr = c*128 + ((r>>3) ^ (c&7))*8 + (r&7). Then 16B coalesced stores
      // (16 consecutive lanes -> 256B contiguous Vt row segment).
      __syncthreads();  // all waves' final frag reads done; reuse smem
#pragma unroll
      for (int nt = 0; nt < 4; nt++) {
        const int c = wn + nt * 16 + frow;          // local n
        const float bvv = bp[by * 128 + c];
        const int cx = c & 7;
#pragma unroll
        for (int mt = 0; mt < 4; mt++) {
          const int r0 = wm + mt * 16 + fq * 4;     // local s (4 contiguous)
          half4v hv;
#pragma unroll
          for (int i = 0; i < 4; i++) hv[i] = (_Float16)(acc[mt][nt][i] + bvv);
          *(half4v*)(smem + c * 128 + (((r0 >> 3) ^ cx) << 3) + (r0 & 7)) = hv;
        }
      }
      __syncthreads();
      // stream out: pass j covers rows c = 16j + tid>>4; lane chunk g = tid&15
      const long bb = bx >> 4;            // batch from s-range
      const int sbase = (bx & 15) * 128;  // s offset within batch
      _Float16* vt = (_Float16*)out + 2 * sO + bb * (2048l * 1024) + sbase;
#pragma unroll
      for (int j = 0; j < 8; j++) {
        const int c = j * 16 + (tid >> 4);
        const int g = tid & 15;
        const int pg = g ^ (c & 7);
        half8 v = *(const half8*)(smem + c * 128 + pg * 8);
        *(half8*)(vt + (long)(by * 128 + c) * 2048 + g * 8) = v;
      }
    }
  }
}

// ---------------- row softmax: S fp16 [rows][2048] -> P fp16 ----------------
__global__ __launch_bounds__(256) void softmax_rows(const _Float16* __restrict__ S,
                                                    _Float16* __restrict__ P) {
  const long row = blockIdx.x;
  const _Float16* src = S + row * 2048;
  _Float16* dst = P + row * 2048;
  const int tid = threadIdx.x;

  half8 v = ((const half8*)src)[tid];  // elems 8t..8t+7
  float f[8];
#pragma unroll
  for (int i = 0; i < 8; i++) f[i] = (float)v[i];

  float m = fmaxf(fmaxf(fmaxf(f[0], f[1]), fmaxf(f[2], f[3])),
                  fmaxf(fmaxf(f[4], f[5]), fmaxf(f[6], f[7])));
#pragma unroll
  for (int o = 32; o > 0; o >>= 1) m = fmaxf(m, __shfl_xor(m, o, 64));
  __shared__ float redm[4];
  if ((tid & 63) == 0) redm[tid >> 6] = m;
  __syncthreads();
  m = fmaxf(fmaxf(redm[0], redm[1]), fmaxf(redm[2], redm[3]));

  float e[8], s = 0.f;
#pragma unroll
  for (int i = 0; i < 8; i++) { e[i] = __expf(f[i] - m); s += e[i]; }
#pragma unroll
  for (int o = 32; o > 0; o >>= 1) s += __shfl_xor(s, o, 64);
  __shared__ float reds[4];
  if ((tid & 63) == 0) reds[tid >> 6] = s;
  __syncthreads();
  s = (reds[0] + reds[1]) + (reds[2] + reds[3]);
  const float inv = 1.f / s;

  half8 h;
#pragma unroll
  for (int i = 0; i < 8; i++) h[i] = (_Float16)(e[i] * inv);
  ((half8*)dst)[tid] = h;
}

extern "C" void kernel_launch(void* const* d_in, const int* in_sizes, int n_in,
                              void* d_out, int out_size, void* d_ws, size_t ws_size,
                              hipStream_t stream) {
  const float* target = (const float*)d_in[0];
  const float* non_target = (const float*)d_in[1];
  const float* Wq = (const float*)d_in[2];
  const float* bq = (const float*)d_in[3];
  const float* Wk = (const float*)d_in[4];
  const float* bk = (const float*)d_in[5];
  const float* Wv = (const float*)d_in[6];
  const float* bv = (const float*)d_in[7];

  char* ws = (char*)d_ws;
  const size_t MB = 1ull << 20;
  _Float16* tgt16 = (_Float16*)(ws);             // 32 MiB
  _Float16* ntg16 = (_Float16*)(ws + 32 * MB);   // 32 MiB
  _Float16* S16 = (_Float16*)(ws);               // 64 MiB (over tgt16/ntg16)
  _Float16* P16 = (_Float16*)(ws + 64 * MB);     // 64 MiB
  _Float16* Q16 = (_Float16*)(ws + 128 * MB);    // 32 MiB
  _Float16* K16 = (_Float16*)(ws + 160 * MB);    // 32 MiB
  _Float16* Vt16 = (_Float16*)(ws + 192 * MB);   // 32 MiB
  _Float16* Wq16 = (_Float16*)(ws + 224 * MB);   // 2 MiB (Wk16/Wv16 contiguous)
  _Float16* Wk16 = (_Float16*)(ws + 226 * MB);
  _Float16* Wv16 = (_Float16*)(ws + 228 * MB);

  // 1. all casts, one launch (17920 blocks: 2x8192 activations + 3x512 weights)
  cast_all<<<17920, 256, 0, stream>>>(target, non_target, Wq, Wk, Wv,
                                      tgt16, ntg16, Wq16, Wk16, Wv16);

  // 2. merged projections, one launch: grid.z in {Q,K,V}.
  //    A: tgt16 (bz=0) / ntg16 (bz>0) via sA=16Mi halfs; B: Wq16+bz*1Mi;
  //    out: Q16+bz*16Mi (Q16,K16,Vt16 contiguous at 128/160/192 MiB).
  gemm_bt<4, 0><<<dim3(128, 8, 3), 256, 0, stream>>>(
      tgt16, Wq16, bq, bk, bv, Q16, 1024, 1024,
      16777216l, 1048576l, 16777216l);

  // 3. scores: per batch [2048,2048] = Q_b x K_b^T (fp16 out), XCD swizzle
  gemm_bt<3, 1><<<dim3(16, 16, 8), 256, 0, stream>>>(
      Q16, K16, nullptr, nullptr, nullptr, S16, 1024, 2048,
      2048l * 1024, 2048l * 1024, 2048l * 2048);

  // 4. softmax rows -> P fp16
  softmax_rows<<<16384, 256, 0, stream>>>(S16, P16);

  // 5. out: per batch [2048,1024] = P_b x Vt_b^T (fp32 out), XCD swizzle
  gemm_bt<2, 2><<<dim3(16, 8, 8), 256, 0, stream>>>(
      P16, Vt16, nullptr, nullptr, nullptr, (float*)d_out, 2048, 1024,
      2048l * 2048, 1024l * 2048, 2048l * 1024);
}

// Round 8
// 452.982 us; speedup vs baseline: 1.2151x; 1.0008x over previous
//
#include <hip/hip_runtime.h>

// CustomAttention: out = softmax((x_t Wq^T + bq)(x_nt Wk^T + bk)^T) (x_nt Wv^T + bv)
// B=8, SQ=SKV=2048, D=1024. fp32 in/out, fp16 MFMA compute (fp32 accumulate).
//
// Round 10: round-9 (453.3 us, best measured) + ONE change: K and V
// projections merged into a dual-B kernel (gemm_kv) sharing one A-staging
// stream -- ntg16 fetched/staged ONCE for both (was twice): 25% fewer staged
// matrices per MFMA, half the barriers per FLOP on 2/3 of projection work.
// Q projection becomes a plain single GEMM launch. Everything else (K-loop,
// XOR swizzle, QK/PV/softmax/cast, XCD swizzles, Vt LDS-transpose epilogue)
// byte-identical to round-9.
// Measured dead, do not revisit: cast/softmax fusion into GEMM staging
// (r6=508, r7=550); 256^2 pipelined schedules (r3/r4 -- all at the ~846 TF
// K=1024-class structure ceiling).
//
// ws layout: [0,32) tgt16 | [32,64) ntg16 (dead after proj; S16 [0,64))
//  [64,128) P16  [128,160) Q16  [160,192) K16  [192,224) Vt16
//  [224,226) Wq16 [226,228) Wk16 [228,230) Wv16

typedef _Float16 half8 __attribute__((ext_vector_type(8)));
typedef _Float16 half4v __attribute__((ext_vector_type(4)));
typedef float floatx4 __attribute__((ext_vector_type(4)));

__device__ __forceinline__ void async_copy16(const _Float16* g, _Float16* l) {
  __builtin_amdgcn_global_load_lds(
      (const __attribute__((address_space(1))) void*)g,
      (__attribute__((address_space(3))) void*)l,
      16, 0, 0);
}

// ---------------- merged cast fp32 -> fp16 (all 5 tensors, one launch) -----
__global__ __launch_bounds__(256) void cast_all(const float* __restrict__ t,
                                                const float* __restrict__ nt,
                                                const float* __restrict__ wq,
                                                const float* __restrict__ wk,
                                                const float* __restrict__ wv,
                                                _Float16* __restrict__ tgt16,
                                                _Float16* __restrict__ ntg16,
                                                _Float16* __restrict__ wq16,
                                                _Float16* __restrict__ wk16,
                                                _Float16* __restrict__ wv16) {
  const int b = blockIdx.x;
  const float* src;
  _Float16* dst;
  long base;
  if (b < 8192)       { src = t;  dst = tgt16; base = (long)b * 2048; }
  else if (b < 16384) { src = nt; dst = ntg16; base = (long)(b - 8192) * 2048; }
  else if (b < 16896) { src = wq; dst = wq16;  base = (long)(b - 16384) * 2048; }
  else if (b < 17408) { src = wk; dst = wk16;  base = (long)(b - 16896) * 2048; }
  else                { src = wv; dst = wv16;  base = (long)(b - 17408) * 2048; }
  const long i = base + (long)threadIdx.x * 8;
  float4 a = *(const float4*)(src + i);
  float4 c = *(const float4*)(src + i + 4);
  half8 h;
  h[0] = (_Float16)a.x; h[1] = (_Float16)a.y; h[2] = (_Float16)a.z; h[3] = (_Float16)a.w;
  h[4] = (_Float16)c.x; h[5] = (_Float16)c.y; h[6] = (_Float16)c.z; h[7] = (_Float16)c.w;
  *(half8*)(dst + i) = h;
}

// ---------------- fp16 BT GEMM: C[m,n] = sum_k A[m,k]*B[n,k] (+bias[n]) ----
// 128x128 tile, BK=64, 256 threads = 4 waves in 2x2 of 64x64, 16x16x32 MFMA.
// LDS: 128 rows x 8 granules (16B), phys granule = logical ^ (row&7).
// OMODE 0: fp16 out row-major + bias (Q projection)
// OMODE 2: fp32 out row-major per batch (PV)
// OMODE 3: fp16 out row-major per batch (QK scores)
// SWZ 1: QK 16x16/batch -> per-XCD 4x8 region. SWZ 2: PV 16x8 -> 4x4 region.
template <int OMODE, int SWZ>
__global__ __launch_bounds__(256, 2) void gemm_bt(const _Float16* __restrict__ A,
                                                  const _Float16* __restrict__ B,
                                                  const float* __restrict__ bias,
                                                  void* __restrict__ out,
                                                  int K, int N,
                                                  long sA, long sB, long sO) {
  __shared__ __attribute__((aligned(16))) _Float16 smem[2 * 128 * 64];
  _Float16* As = smem;
  _Float16* Bs = smem + 8192;

  const int tid = threadIdx.x;
  const int lane = tid & 63;
  const int wave = tid >> 6;
  const long bz = blockIdx.z;

  int bx = blockIdx.x, by = blockIdx.y;
  if (SWZ == 1) {  // grid (16,16): XCD g owns 4x8 region
    const int h = bx + 16 * by, g = h & 7, idx = h >> 3;
    bx = (g & 3) * 4 + (idx & 3);
    by = (g >> 2) * 8 + (idx >> 2);
  } else if (SWZ == 2) {  // grid (16,8): XCD g owns 4x4 region
    const int h = bx + 16 * by, g = h & 7, idx = h >> 3;
    bx = (g & 3) * 4 + (idx & 3);
    by = (g >> 2) * 4 + (idx >> 2);
  }

  const _Float16* Ab = A + bz * sA + (long)bx * 128 * K;
  const _Float16* Bb = B + bz * sB + (long)by * 128 * K;

  const int wm = (wave & 1) * 64;
  const int wn = (wave >> 1) * 64;
  const int frow = lane & 15;
  const int fq = lane >> 4;
  const int fsw = frow & 7;

  floatx4 acc[4][4];
#pragma unroll
  for (int mt = 0; mt < 4; mt++)
#pragma unroll
    for (int nt = 0; nt < 4; nt++)
      acc[mt][nt] = (floatx4){0.f, 0.f, 0.f, 0.f};

  const int sr = tid >> 3;
  const int gl = (tid & 7) ^ (sr & 7);
  const long gOffBase = (long)sr * K + gl * 8;
  const int ldsOff = tid * 8;

  for (int k0 = 0; k0 < K; k0 += 64) {
    __syncthreads();
#pragma unroll
    for (int j = 0; j < 4; j++) {
      async_copy16(Ab + gOffBase + (long)(32 * j) * K + k0, As + ldsOff + j * 2048);
      async_copy16(Bb + gOffBase + (long)(32 * j) * K + k0, Bs + ldsOff + j * 2048);
    }
    __syncthreads();

#pragma unroll
    for (int h = 0; h < 2; h++) {
      half8 af[4], bf[4];
#pragma unroll
      for (int mt = 0; mt < 4; mt++)
        af[mt] = *(const half8*)(As + (wm + mt * 16 + frow) * 64 + ((h * 4 + fq) ^ fsw) * 8);
#pragma unroll
      for (int nt = 0; nt < 4; nt++)
        bf[nt] = *(const half8*)(Bs + (wn + nt * 16 + frow) * 64 + ((h * 4 + fq) ^ fsw) * 8);
#pragma unroll
      for (int mt = 0; mt < 4; mt++)
#pragma unroll
        for (int nt = 0; nt < 4; nt++)
          acc[mt][nt] = __builtin_amdgcn_mfma_f32_16x16x32_f16(af[mt], bf[nt], acc[mt][nt], 0, 0, 0);
    }
  }

  // C/D layout: acc[mt][nt][i] = C[wm+mt*16+fq*4+i][wn+nt*16+frow]
  if (OMODE == 2 || OMODE == 3) {
#pragma unroll
    for (int nt = 0; nt < 4; nt++) {
      const int n = by * 128 + wn + nt * 16 + frow;
#pragma unroll
      for (int mt = 0; mt < 4; mt++) {
        const int rbase = bx * 128 + wm + mt * 16 + fq * 4;
#pragma unroll
        for (int i = 0; i < 4; i++) {
          if (OMODE == 2)
            ((float*)out + bz * sO)[(long)(rbase + i) * N + n] = acc[mt][nt][i];
          else
            ((_Float16*)out + bz * sO)[(long)(rbase + i) * N + n] = (_Float16)acc[mt][nt][i];
        }
      }
    }
  } else {  // OMODE 0: fp16 row-major + bias
#pragma unroll
    for (int nt = 0; nt < 4; nt++) {
      const int n = by * 128 + wn + nt * 16 + frow;
      const float bvv = bias[n];
#pragma unroll
      for (int mt = 0; mt < 4; mt++) {
        const int rbase = bx * 128 + wm + mt * 16 + fq * 4;
#pragma unroll
        for (int i = 0; i < 4; i++)
          ((_Float16*)out)[(long)(rbase + i) * N + n] = (_Float16)(acc[mt][nt][i] + bvv);
      }
    }
  }
}

// ---------------- dual-B GEMM: K and V projections sharing A staging -------
// C_K = A x Wk^T + bk (row-major fp16), C_V = A x Wv^T + bv (V-transposed via
// LDS-transpose epilogue). A = ntg16 staged ONCE per K-step; 32 MFMA/step.
__global__ __launch_bounds__(256, 2) void gemm_kv(const _Float16* __restrict__ A,
                                                  const _Float16* __restrict__ Bk,
                                                  const _Float16* __restrict__ Bv,
                                                  const float* __restrict__ biasK,
                                                  const float* __restrict__ biasV,
                                                  _Float16* __restrict__ Kout,
                                                  _Float16* __restrict__ Vt) {
  const int K = 1024, N = 1024;
  __shared__ __attribute__((aligned(16))) _Float16 smem[3 * 128 * 64];  // 48 KB
  _Float16* As = smem;
  _Float16* BsK = smem + 8192;
  _Float16* BsV = smem + 16384;

  const int tid = threadIdx.x;
  const int lane = tid & 63;
  const int wave = tid >> 6;
  const int bx = blockIdx.x, by = blockIdx.y;

  const _Float16* Ab = A + (long)bx * 128 * K;
  const _Float16* BkB = Bk + (long)by * 128 * K;
  const _Float16* BvB = Bv + (long)by * 128 * K;

  const int wm = (wave & 1) * 64;
  const int wn = (wave >> 1) * 64;
  const int frow = lane & 15;
  const int fq = lane >> 4;
  const int fsw = frow & 7;

  floatx4 accK[4][4], accV[4][4];
#pragma unroll
  for (int mt = 0; mt < 4; mt++)
#pragma unroll
    for (int nt = 0; nt < 4; nt++) {
      accK[mt][nt] = (floatx4){0.f, 0.f, 0.f, 0.f};
      accV[mt][nt] = (floatx4){0.f, 0.f, 0.f, 0.f};
    }

  const int sr = tid >> 3;
  const int gl = (tid & 7) ^ (sr & 7);
  const long gOffBase = (long)sr * K + gl * 8;
  const int ldsOff = tid * 8;

  for (int k0 = 0; k0 < K; k0 += 64) {
    __syncthreads();
#pragma unroll
    for (int j = 0; j < 4; j++) {
      async_copy16(Ab + gOffBase + (long)(32 * j) * K + k0, As + ldsOff + j * 2048);
      async_copy16(BkB + gOffBase + (long)(32 * j) * K + k0, BsK + ldsOff + j * 2048);
      async_copy16(BvB + gOffBase + (long)(32 * j) * K + k0, BsV + ldsOff + j * 2048);
    }
    __syncthreads();

#pragma unroll
    for (int h = 0; h < 2; h++) {
      half8 af[4], bfK[4], bfV[4];
#pragma unroll
      for (int mt = 0; mt < 4; mt++)
        af[mt] = *(const half8*)(As + (wm + mt * 16 + frow) * 64 + ((h * 4 + fq) ^ fsw) * 8);
#pragma unroll
      for (int nt = 0; nt < 4; nt++)
        bfK[nt] = *(const half8*)(BsK + (wn + nt * 16 + frow) * 64 + ((h * 4 + fq) ^ fsw) * 8);
#pragma unroll
      for (int mt = 0; mt < 4; mt++)
#pragma unroll
        for (int nt = 0; nt < 4; nt++)
          accK[mt][nt] = __builtin_amdgcn_mfma_f32_16x16x32_f16(af[mt], bfK[nt], accK[mt][nt], 0, 0, 0);
#pragma unroll
      for (int nt = 0; nt < 4; nt++)
        bfV[nt] = *(const half8*)(BsV + (wn + nt * 16 + frow) * 64 + ((h * 4 + fq) ^ fsw) * 8);
#pragma unroll
      for (int mt = 0; mt < 4; mt++)
#pragma unroll
        for (int nt = 0; nt < 4; nt++)
          accV[mt][nt] = __builtin_amdgcn_mfma_f32_16x16x32_f16(af[mt], bfV[nt], accV[mt][nt], 0, 0, 0);
    }
  }

  // K epilogue: fp16 row-major + bias (coalesces through L2 like r9's Q/K).
#pragma unroll
  for (int nt = 0; nt < 4; nt++) {
    const int n = by * 128 + wn + nt * 16 + frow;
    const float bvv = biasK[n];
#pragma unroll
    for (int mt = 0; mt < 4; mt++) {
      const int rbase = bx * 128 + wm + mt * 16 + fq * 4;
#pragma unroll
      for (int i = 0; i < 4; i++)
        Kout[(long)(rbase + i) * N + n] = (_Float16)(accK[mt][nt][i] + bvv);
    }
  }

  // V epilogue: LDS transpose (r9-verified pattern) -> coalesced 16B stores.
  // T[c][r] halfs at smem + c*128 + ((r>>3)^(c&7))*8 + (r&7)  (32 KB, reuses
  // As+BsK region; all frag reads done -- guarded by syncthreads).
  __syncthreads();
#pragma unroll
  for (int nt = 0; nt < 4; nt++) {
    const int c = wn + nt * 16 + frow;          // local n
    const float bvv = biasV[by * 128 + c];
    const int cx = c & 7;
#pragma unroll
    for (int mt = 0; mt < 4; mt++) {
      const int r0 = wm + mt * 16 + fq * 4;     // local s (4 contiguous)
      half4v hv;
#pragma unroll
      for (int i = 0; i < 4; i++) hv[i] = (_Float16)(accV[mt][nt][i] + bvv);
      *(half4v*)(smem + c * 128 + (((r0 >> 3) ^ cx) << 3) + (r0 & 7)) = hv;
    }
  }
  __syncthreads();
  const long bb = bx >> 4;            // batch from s-range
  const int sbase = (bx & 15) * 128;  // s offset within batch
  _Float16* vt = Vt + bb * (2048l * 1024) + sbase;
#pragma unroll
  for (int j = 0; j < 8; j++) {
    const int c = j * 16 + (tid >> 4);
    const int g = tid & 15;
    const int pg = g ^ (c & 7);
    half8 v = *(const half8*)(smem + c * 128 + pg * 8);
    *(half8*)(vt + (long)(by * 128 + c) * 2048 + g * 8) = v;
  }
}

// ---------------- row softmax: S fp16 [rows][2048] -> P fp16 ----------------
__global__ __launch_bounds__(256) void softmax_rows(const _Float16* __restrict__ S,
                                                    _Float16* __restrict__ P) {
  const long row = blockIdx.x;
  const _Float16* src = S + row * 2048;
  _Float16* dst = P + row * 2048;
  const int tid = threadIdx.x;

  half8 v = ((const half8*)src)[tid];  // elems 8t..8t+7
  float f[8];
#pragma unroll
  for (int i = 0; i < 8; i++) f[i] = (float)v[i];

  float m = fmaxf(fmaxf(fmaxf(f[0], f[1]), fmaxf(f[2], f[3])),
                  fmaxf(fmaxf(f[4], f[5]), fmaxf(f[6], f[7])));
#pragma unroll
  for (int o = 32; o > 0; o >>= 1) m = fmaxf(m, __shfl_xor(m, o, 64));
  __shared__ float redm[4];
  if ((tid & 63) == 0) redm[tid >> 6] = m;
  __syncthreads();
  m = fmaxf(fmaxf(redm[0], redm[1]), fmaxf(redm[2], redm[3]));

  float e[8], s = 0.f;
#pragma unroll
  for (int i = 0; i < 8; i++) { e[i] = __expf(f[i] - m); s += e[i]; }
#pragma unroll
  for (int o = 32; o > 0; o >>= 1) s += __shfl_xor(s, o, 64);
  __shared__ float reds[4];
  if ((tid & 63) == 0) reds[tid >> 6] = s;
  __syncthreads();
  s = (reds[0] + reds[1]) + (reds[2] + reds[3]);
  const float inv = 1.f / s;

  half8 h;
#pragma unroll
  for (int i = 0; i < 8; i++) h[i] = (_Float16)(e[i] * inv);
  ((half8*)dst)[tid] = h;
}

extern "C" void kernel_launch(void* const* d_in, const int* in_sizes, int n_in,
                              void* d_out, int out_size, void* d_ws, size_t ws_size,
                              hipStream_t stream) {
  const float* target = (const float*)d_in[0];
  const float* non_target = (const float*)d_in[1];
  const float* Wq = (const float*)d_in[2];
  const float* bq = (const float*)d_in[3];
  const float* Wk = (const float*)d_in[4];
  const float* bk = (const float*)d_in[5];
  const float* Wv = (const float*)d_in[6];
  const float* bv = (const float*)d_in[7];

  char* ws = (char*)d_ws;
  const size_t MB = 1ull << 20;
  _Float16* tgt16 = (_Float16*)(ws);             // 32 MiB
  _Float16* ntg16 = (_Float16*)(ws + 32 * MB);   // 32 MiB
  _Float16* S16 = (_Float16*)(ws);               // 64 MiB (over tgt16/ntg16)
  _Float16* P16 = (_Float16*)(ws + 64 * MB);     // 64 MiB
  _Float16* Q16 = (_Float16*)(ws + 128 * MB);    // 32 MiB
  _Float16* K16 = (_Float16*)(ws + 160 * MB);    // 32 MiB
  _Float16* Vt16 = (_Float16*)(ws + 192 * MB);   // 32 MiB
  _Float16* Wq16 = (_Float16*)(ws + 224 * MB);   // 2 MiB
  _Float16* Wk16 = (_Float16*)(ws + 226 * MB);
  _Float16* Wv16 = (_Float16*)(ws + 228 * MB);

  // 1. all casts, one launch
  cast_all<<<17920, 256, 0, stream>>>(target, non_target, Wq, Wk, Wv,
                                      tgt16, ntg16, Wq16, Wk16, Wv16);

  // 2a. Q projection: [16384,1024] x [1024,1024]^T + bq -> Q16 (fp16)
  gemm_bt<0, 0><<<dim3(128, 8, 1), 256, 0, stream>>>(
      tgt16, Wq16, bq, Q16, 1024, 1024, 0, 0, 0);

  // 2b. K+V projections, shared A staging: ntg16 x {Wk,Wv}^T + {bk,bv}
  gemm_kv<<<dim3(128, 8), 256, 0, stream>>>(ntg16, Wk16, Wv16, bk, bv, K16, Vt16);

  // 3. scores: per batch [2048,2048] = Q_b x K_b^T (fp16 out), XCD swizzle
  gemm_bt<3, 1><<<dim3(16, 16, 8), 256, 0, stream>>>(
      Q16, K16, nullptr, S16, 1024, 2048,
      2048l * 1024, 2048l * 1024, 2048l * 2048);

  // 4. softmax rows -> P fp16
  softmax_rows<<<16384, 256, 0, stream>>>(S16, P16);

  // 5. out: per batch [2048,1024] = P_b x Vt_b^T (fp32 out), XCD swizzle
  gemm_bt<2, 2><<<dim3(16, 8, 8), 256, 0, stream>>>(
      P16, Vt16, nullptr, (float*)d_out, 2048, 1024,
      2048l * 2048, 1024l * 2048, 2048l * 1024);
}